// Round 15
// baseline (76.265 us; speedup 1.0000x reference)
//
#include <hip/hip_runtime.h>
#include <hip/hip_bf16.h>

typedef unsigned short u16;
typedef __attribute__((ext_vector_type(4))) unsigned short u16x4;
typedef __attribute__((ext_vector_type(8))) unsigned short u16x8;
typedef __attribute__((ext_vector_type(8))) short bf16x8;
typedef __attribute__((ext_vector_type(4))) float f32x4;

#define AS1 __attribute__((address_space(1)))
#define AS3 __attribute__((address_space(3)))

__device__ __forceinline__ float b2f(u16 v) {
    return __uint_as_float(((unsigned)v) << 16);
}
__device__ __forceinline__ u16 f2bf(float f) {
    unsigned u = __float_as_uint(f);
    unsigned r = (u + 0x7fffu + ((u >> 16) & 1u)) >> 16;
    return (u16)r;
}

// ---------------------------------------------------------------------------
// prep_all: one launch for all independent preprocessing.
//   blocks [0,2048)    : LayerNorm x -> xn (bf16), 4 rows/block
//   blocks [2048,3072) : media f32 -> bf16
//   blocks [3072,3840) : weight transpose-convert (Wq,Wkv,Wo) -> (N,K) bf16
//   block  3840        : mask detect {bool8,int32,f32} + ballot-compact idx
//                        (idx padded with 0 to a multiple of 128)
// ---------------------------------------------------------------------------
__global__ __launch_bounds__(256) void prep_all(
    const float* __restrict__ x, const float* __restrict__ media,
    const unsigned char* __restrict__ mask,
    const float* __restrict__ ln_g, const float* __restrict__ ln_b,
    const float* __restrict__ Wq, const float* __restrict__ Wkv,
    const float* __restrict__ Wo,
    u16* __restrict__ xn, u16* __restrict__ mediab,
    unsigned char* __restrict__ mask8, int* __restrict__ idx,
    int* __restrict__ cnts,
    u16* __restrict__ wqt, u16* __restrict__ wkvt, u16* __restrict__ wot) {
    __shared__ u16 T[64][72];
    __shared__ int c0s, c1s;
    const int bid = blockIdx.x, tid = threadIdx.x;

    if (bid < 2048) {  // ---- LayerNorm ----
        const int lane = tid & 63;
        const int row = bid * 4 + (tid >> 6);
        const float* xr = x + (size_t)row * 1024;
        float v[16];
        float sum = 0.f, sq = 0.f;
#pragma unroll
        for (int c = 0; c < 4; ++c) {
            float4 u = ((const float4*)xr)[c * 64 + lane];
            v[c * 4 + 0] = u.x; v[c * 4 + 1] = u.y; v[c * 4 + 2] = u.z; v[c * 4 + 3] = u.w;
            sum += u.x + u.y + u.z + u.w;
            sq += u.x * u.x + u.y * u.y + u.z * u.z + u.w * u.w;
        }
#pragma unroll
        for (int o = 1; o < 64; o <<= 1) {
            sum += __shfl_xor(sum, o, 64);
            sq += __shfl_xor(sq, o, 64);
        }
        float mean = sum * (1.f / 1024.f);
        float var = sq * (1.f / 1024.f) - mean * mean;
        float rs = rsqrtf(var + 1e-5f);
        u16* yr = xn + (size_t)row * 1024;
#pragma unroll
        for (int c = 0; c < 4; ++c) {
            float4 ug = ((const float4*)ln_g)[c * 64 + lane];
            float4 ub = ((const float4*)ln_b)[c * 64 + lane];
            u16x4 o;
            o[0] = f2bf((v[c * 4 + 0] - mean) * rs * ug.x + ub.x);
            o[1] = f2bf((v[c * 4 + 1] - mean) * rs * ug.y + ub.y);
            o[2] = f2bf((v[c * 4 + 2] - mean) * rs * ug.z + ub.z);
            o[3] = f2bf((v[c * 4 + 3] - mean) * rs * ug.w + ub.w);
            *(u16x4*)(yr + c * 256 + lane * 4) = o;
        }
    } else if (bid < 3072) {  // ---- media f32->bf16 ----
        int i = (bid - 2048) * 256 + tid;
        float4 a = ((const float4*)media)[i * 2];
        float4 b = ((const float4*)media)[i * 2 + 1];
        u16x8 o;
        o[0] = f2bf(a.x); o[1] = f2bf(a.y); o[2] = f2bf(a.z); o[3] = f2bf(a.w);
        o[4] = f2bf(b.x); o[5] = f2bf(b.y); o[6] = f2bf(b.z); o[7] = f2bf(b.w);
        ((u16x8*)mediab)[i] = o;
    } else if (bid < 3840) {  // ---- weight transpose-convert ----
        const int t = bid - 3072;
        const int z = t >> 8, rem = t & 255;
        const float* in; u16* out; int K, N;
        if (z == 0)      { in = Wq;  out = wqt;  K = 1024; N = 512; }
        else if (z == 1) { in = Wkv; out = wkvt; K = 1024; N = 1024; }
        else             { in = Wo;  out = wot;  K = 512;  N = 1024; }
        const int k0 = (rem >> 4) * 64, n0 = (rem & 15) * 64;
        if (k0 >= K || n0 >= N) return;
#pragma unroll
        for (int p = 0; p < 4; ++p) {
            int kr = p * 16 + (tid >> 4);
            float4 u = *(const float4*)(in + (size_t)(k0 + kr) * N + n0 + (tid & 15) * 4);
            u16x4 o4;
            o4[0] = f2bf(u.x); o4[1] = f2bf(u.y); o4[2] = f2bf(u.z); o4[3] = f2bf(u.w);
            *(u16x4*)(&T[kr][(tid & 15) * 4]) = o4;
        }
        __syncthreads();
        const int n = tid >> 2, kc = (tid & 3) * 16;
#pragma unroll
        for (int hh = 0; hh < 2; ++hh) {
            u16x8 o;
#pragma unroll
            for (int i = 0; i < 8; ++i) o[i] = T[kc + hh * 8 + i][n];
            *(u16x8*)(out + (size_t)(n0 + n) * K + k0 + kc + hh * 8) = o;
        }
    } else {  // ---- mask detect + compact ----
        if (tid == 0) { c0s = 0; c1s = 0; }
        __syncthreads();
        int a0 = 0, a1 = 0;
        for (int i = tid; i < 2048; i += 256) {
            if (mask[i]) {
                int cl = i & 3;
                if (cl == 0) a0 = 1;
                else if (cl == 1) a1 = 1;
            }
        }
        if (a0) atomicOr(&c0s, 1);
        if (a1) atomicOr(&c1s, 1);
        __syncthreads();
        int fmt = c1s ? 1 : (c0s ? 0 : 2);  // 1=bool8, 0=int32, 2=float32
        for (int e = tid; e < 2048; e += 256) {
            unsigned char v;
            if (fmt == 1)      v = (mask[e] != 0);
            else if (fmt == 0) v = (((const int*)mask)[e] != 0);
            else               v = (((const float*)mask)[e] != 0.f);
            mask8[e] = v;
        }
        __syncthreads();
        const int wv = tid >> 6, l = tid & 63;
        int off = 0;
#pragma unroll
        for (int c = 0; c < 8; ++c) {
            int key = c * 64 + l;
            bool v = mask8[wv * 512 + key] != 0;
            unsigned long long m = __ballot(v);
            int rank = __popcll(m & ((1ull << l) - 1ull));
            if (v) idx[wv * 512 + off + rank] = key;
            off += __popcll(m);
        }
        if (l == 0) cnts[wv] = off;
        int nt = (off + 127) & ~127;        // pad to 128 (KV-GEMM row tile)
        for (int p = off + l; p < nt; p += 64) idx[wv * 512 + p] = 0;
    }
}

// ---------------------------------------------------------------------------
// GEMM tile body: global_load_lds staging + XOR-swizzled LDS + DOUBLE-BUFFER
// with counted vmcnt (T4). At 1-2 blocks/CU there is no TLP to hide the
// vmcnt(0) drain; prefetching tile t+1 before computing tile t and waiting
// vmcnt(8) (oldest 8 = current tile's loads) keeps the prefetch in flight
// across the raw s_barrier. sched_barrier(0) after the waitcnt per rule #18.
// C(128x128 tile) = A(MxK) @ Bt(NxK)^T, BK=64, 4 waves.
// GATHER=1: A row g is A[ridx[row0+g]].
// ---------------------------------------------------------------------------
template <int OUTF32, int GATHER>
__device__ __forceinline__ void gemm_tile_g(u16* As, u16* Bs,  // each 2*128*64
                                            const u16* __restrict__ A,
                                            const u16* __restrict__ Bt,
                                            void* __restrict__ Cv,
                                            int N, int K, int row0, int col0,
                                            float scale,
                                            const int* __restrict__ ridx) {
    const int tid = threadIdx.x;
    const int l = tid & 63, w = tid >> 6;
    const int l15 = l & 15, l4 = l >> 4;
    const int wm = w >> 1, wn = w & 1;
    const int lr = l >> 3;                 // row-within-8 for staging
    const int cs = ((l & 7) ^ lr) * 8;     // pre-swizzled source slot (elems)

    // per-thread A source rows (loop-invariant over k0)
    int arow[4];
#pragma unroll
    for (int i = 0; i < 4; ++i) {
        int g = w * 32 + i * 8 + lr;
        arow[i] = GATHER ? ridx[row0 + g] : (row0 + g);
    }

    f32x4 zero = {0.f, 0.f, 0.f, 0.f};
    f32x4 acc[4][4];
#pragma unroll
    for (int i = 0; i < 4; ++i)
#pragma unroll
        for (int j = 0; j < 4; ++j) acc[i][j] = zero;

    const int rsw = l15 & 7;               // row&7 for all fragment rows
    const int nt = K >> 6;                 // K-steps of 64

    // ---- prologue: stage tile 0 into buffer 0 ----
#pragma unroll
    for (int i = 0; i < 4; ++i) {
        int r = w * 32 + i * 8;
        __builtin_amdgcn_global_load_lds(
            (const AS1 void*)(A + (size_t)arow[i] * K + cs),
            (AS3 void*)(As + r * 64), 16, 0, 0);
        __builtin_amdgcn_global_load_lds(
            (const AS1 void*)(Bt + (size_t)(col0 + r + lr) * K + cs),
            (AS3 void*)(Bs + r * 64), 16, 0, 0);
    }

    for (int t = 0; t < nt; ++t) {
        const int cur = (t & 1) * (128 * 64);
        if (t + 1 < nt) {
            const int nxt = ((t + 1) & 1) * (128 * 64);
            const int k1 = (t + 1) << 6;
#pragma unroll
            for (int i = 0; i < 4; ++i) {
                int r = w * 32 + i * 8;
                __builtin_amdgcn_global_load_lds(
                    (const AS1 void*)(A + (size_t)arow[i] * K + k1 + cs),
                    (AS3 void*)(As + nxt + r * 64), 16, 0, 0);
                __builtin_amdgcn_global_load_lds(
                    (const AS1 void*)(Bt + (size_t)(col0 + r + lr) * K + k1 + cs),
                    (AS3 void*)(Bs + nxt + r * 64), 16, 0, 0);
            }
            asm volatile("s_waitcnt vmcnt(8)");   // current tile retired; prefetch in flight
        } else {
            asm volatile("s_waitcnt vmcnt(0)");
        }
        __builtin_amdgcn_sched_barrier(0);        // rule #18: no hoisting past waitcnt
        __builtin_amdgcn_s_barrier();             // buf[cur] visible to all waves
        __builtin_amdgcn_sched_barrier(0);

#pragma unroll
        for (int h = 0; h < 2; ++h) {      // two K=32 sub-steps
            bf16x8 aF[4], bF[4];
#pragma unroll
            for (int m = 0; m < 4; ++m) {
                int s = (h * 4 + l4) ^ rsw;             // swizzled slot
                aF[m] = *(const bf16x8*)(As + cur + (wm * 64 + m * 16 + l15) * 64 + s * 8);
                bF[m] = *(const bf16x8*)(Bs + cur + (wn * 64 + m * 16 + l15) * 64 + s * 8);
            }
#pragma unroll
            for (int m = 0; m < 4; ++m)
#pragma unroll
                for (int n = 0; n < 4; ++n)
                    acc[m][n] = __builtin_amdgcn_mfma_f32_16x16x32_bf16(aF[m], bF[n], acc[m][n], 0, 0, 0);
        }
        __builtin_amdgcn_s_barrier();             // all waves done reading buf[cur]
    }
#pragma unroll
    for (int m = 0; m < 4; ++m)
#pragma unroll
        for (int n = 0; n < 4; ++n) {
            int row = row0 + wm * 64 + m * 16 + l4 * 4;
            int col = col0 + wn * 64 + n * 16 + l15;
#pragma unroll
            for (int r = 0; r < 4; ++r) {
                float vv = acc[m][n][r] * scale;
                if (OUTF32)
                    ((float*)Cv)[(size_t)(row + r) * N + col] = vv;
                else
                    ((u16*)Cv)[(size_t)(row + r) * N + col] = f2bf(vv);
            }
        }
}

// ---------------------------------------------------------------------------
// Merged Q + compacted-KV projection GEMM.
//   blocks [0,256)   : qb = (xn @ Wq) * 0.125   (8192x512, K=1024)
//   blocks [256,384) : kvb[b][j] = mediab[b][idx[b][j]] @ Wkv (valid keys)
// ---------------------------------------------------------------------------
__global__ __launch_bounds__(256, 2) void qkv_gemm(const u16* __restrict__ xn,
                                                   const u16* __restrict__ wqt,
                                                   u16* __restrict__ qb,
                                                   const u16* __restrict__ mediab,
                                                   const u16* __restrict__ wkvt,
                                                   u16* __restrict__ kvb,
                                                   const int* __restrict__ idx,
                                                   const int* __restrict__ cnts) {
    __shared__ u16 As[2 * 128 * 64];
    __shared__ u16 Bs[2 * 128 * 64];
    const int b = blockIdx.x;
    if (b < 256) {
        gemm_tile_g<0, 0>(As, Bs, xn, wqt, (void*)qb, 512, 1024,
                          (b >> 2) * 128, (b & 3) * 128, 0.125f, nullptr);
    } else {
        const int t = b - 256;
        const int bbi = t >> 5, rem = t & 31;
        const int row0 = (rem >> 3) * 128, col0 = (rem & 7) * 128;
        const int nt128 = (cnts[bbi] + 127) & ~127;
        if (row0 >= nt128) return;
        gemm_tile_g<0, 1>(As, Bs, mediab + (size_t)bbi * 512 * 1024, wkvt,
                          (void*)(kvb + (size_t)bbi * 512 * 1024), 1024, 1024,
                          row0, col0, 1.f, idx + bbi * 512);
    }
}

// ---------------------------------------------------------------------------
// Output projection: out = ao @ Wo  (8192x1024, K=512), f32 store.
// ---------------------------------------------------------------------------
__global__ __launch_bounds__(256, 2) void o_gemm(const u16* __restrict__ ao,
                                                 const u16* __restrict__ wot,
                                                 float* __restrict__ out) {
    __shared__ u16 As[2 * 128 * 64];
    __shared__ u16 Bs[2 * 128 * 64];
    gemm_tile_g<1, 0>(As, Bs, ao, wot, (void*)out, 1024, 512,
                      (int)blockIdx.y * 128, (int)blockIdx.x * 128, 1.f, nullptr);
}

// ---------------------------------------------------------------------------
// MFMA flash attention over PRE-COMPACTED contiguous K/V. Block = 4 waves,
// QBLK=64 (16 q-rows/wave), KVBLK=64. Grid (32, 8 heads, 4 batch).
// Defer-max (T13) + per-lane lrun partial (epilogue-reduced).
// ---------------------------------------------------------------------------
__global__ __launch_bounds__(256) void attn_mfma(const u16* __restrict__ qb,
                                                 const u16* __restrict__ kvb,
                                                 const int* __restrict__ cnts,
                                                 u16* __restrict__ ao) {
    __shared__ u16 Ks[64][72];      // K tile [j][d]
    __shared__ u16 Vt[64][72];      // V^T tile [d][j]
    __shared__ u16 Pl[4][16][72];   // per-wave P [q][j]
    const int tid = threadIdx.x;
    const int l = tid & 63, w = tid >> 6;
    const int l15 = l & 15, l4 = l >> 4;
    const int h = blockIdx.y, bbi = blockIdx.z;
    const int n0 = blockIdx.x * 64;
    const int cnt = cnts[bbi];

    const u16* qp = qb + ((size_t)(bbi * 2048 + n0 + w * 16 + l15)) * 512 + h * 64;
    const bf16x8 qf0 = *(const bf16x8*)(qp + l4 * 8);
    const bf16x8 qf1 = *(const bf16x8*)(qp + 32 + l4 * 8);

    const f32x4 zero = {0.f, 0.f, 0.f, 0.f};
    f32x4 acc[4];
#pragma unroll
    for (int dt = 0; dt < 4; ++dt) acc[dt] = zero;
    float mrun[4] = {-3.0e38f, -3.0e38f, -3.0e38f, -3.0e38f};
    float lrun[4] = {0.f, 0.f, 0.f, 0.f};   // per-lane partial denominator

    const int kj = tid >> 3, kd = (tid & 7) * 8;
    const int vj = tid & 63, vd = (tid >> 6) * 16;
    const u16* kbase = kvb + ((size_t)bbi * 512) * 1024 + h * 64;

    for (int j0 = 0; j0 < cnt; j0 += 64) {
        __syncthreads();
#pragma unroll
        for (int p = 0; p < 2; ++p) {
            int r = kj + p * 32;
            u16x8 kv_ = *(const u16x8*)(kbase + (size_t)(j0 + r) * 1024 + kd);
            *(u16x8*)(&Ks[r][kd]) = kv_;
        }
        {
#pragma unroll
            for (int p = 0; p < 2; ++p) {
                u16x8 vv = *(const u16x8*)(kbase + (size_t)(j0 + vj) * 1024 + 512 + vd + p * 8);
#pragma unroll
                for (int i = 0; i < 8; ++i) Vt[vd + p * 8 + i][vj] = vv[i];
            }
        }
        __syncthreads();

        // ---- S = Q K^T (16q x 64j), 8 MFMA ----
        f32x4 s[4];
        float mv[4];
#pragma unroll
        for (int jt = 0; jt < 4; ++jt) {
            bf16x8 kf0 = *(const bf16x8*)(&Ks[jt * 16 + l15][l4 * 8]);
            bf16x8 kf1 = *(const bf16x8*)(&Ks[jt * 16 + l15][32 + l4 * 8]);
            s[jt] = __builtin_amdgcn_mfma_f32_16x16x32_bf16(qf0, kf0, zero, 0, 0, 0);
            s[jt] = __builtin_amdgcn_mfma_f32_16x16x32_bf16(qf1, kf1, s[jt], 0, 0, 0);
            mv[jt] = (j0 + jt * 16 + l15 < cnt) ? 0.f : -3.0e38f;
        }

        // ---- defer-max test (one ballot for the whole wave) ----
        float sv[4][4];   // [r][jt]
        float pmax[4];
        bool cond = true;
#pragma unroll
        for (int r = 0; r < 4; ++r) {
#pragma unroll
            for (int jt = 0; jt < 4; ++jt) sv[r][jt] = s[jt][r] + mv[jt];
            pmax[r] = fmaxf(fmaxf(sv[r][0], sv[r][1]), fmaxf(sv[r][2], sv[r][3]));
            cond = cond && (pmax[r] <= mrun[r] + 8.f);
        }
        if (__all(cond)) {
            // ---- fast path: no reduction, no rescale ----
#pragma unroll
            for (int r = 0; r < 4; ++r) {
                float p0 = __expf(sv[r][0] - mrun[r]);
                float p1 = __expf(sv[r][1] - mrun[r]);
                float p2 = __expf(sv[r][2] - mrun[r]);
                float p3 = __expf(sv[r][3] - mrun[r]);
                lrun[r] += (p0 + p1) + (p2 + p3);
                Pl[w][l4 * 4 + r][l15] = f2bf(p0);
                Pl[w][l4 * 4 + r][16 + l15] = f2bf(p1);
                Pl[w][l4 * 4 + r][32 + l15] = f2bf(p2);
                Pl[w][l4 * 4 + r][48 + l15] = f2bf(p3);
            }
        } else {
            // ---- slow path: full online-softmax update ----
#pragma unroll
            for (int r = 0; r < 4; ++r) {
                float tmax = pmax[r];
#pragma unroll
                for (int o = 1; o < 16; o <<= 1) tmax = fmaxf(tmax, __shfl_xor(tmax, o, 64));
                float mn = fmaxf(mrun[r], tmax);
                float corr = __expf(mrun[r] - mn);
                mrun[r] = mn;
                float p0 = __expf(sv[r][0] - mn);
                float p1 = __expf(sv[r][1] - mn);
                float p2 = __expf(sv[r][2] - mn);
                float p3 = __expf(sv[r][3] - mn);
                lrun[r] = lrun[r] * corr + (p0 + p1) + (p2 + p3);
#pragma unroll
                for (int dt = 0; dt < 4; ++dt) acc[dt][r] *= corr;
                Pl[w][l4 * 4 + r][l15] = f2bf(p0);
                Pl[w][l4 * 4 + r][16 + l15] = f2bf(p1);
                Pl[w][l4 * 4 + r][32 + l15] = f2bf(p2);
                Pl[w][l4 * 4 + r][48 + l15] = f2bf(p3);
            }
        }
        // ---- O += P V (8 MFMA) ----
        bf16x8 pf0 = *(const bf16x8*)(&Pl[w][l15][l4 * 8]);
        bf16x8 pf1 = *(const bf16x8*)(&Pl[w][l15][32 + l4 * 8]);
#pragma unroll
        for (int dt = 0; dt < 4; ++dt) {
            bf16x8 vf0 = *(const bf16x8*)(&Vt[dt * 16 + l15][l4 * 8]);
            bf16x8 vf1 = *(const bf16x8*)(&Vt[dt * 16 + l15][32 + l4 * 8]);
            acc[dt] = __builtin_amdgcn_mfma_f32_16x16x32_bf16(pf0, vf0, acc[dt], 0, 0, 0);
            acc[dt] = __builtin_amdgcn_mfma_f32_16x16x32_bf16(pf1, vf1, acc[dt], 0, 0, 0);
        }
    }

    // ---- epilogue: reduce per-lane lrun across the 16-lane key-column group
    float inv[4];
#pragma unroll
    for (int r = 0; r < 4; ++r) {
        float lt = lrun[r];
#pragma unroll
        for (int o = 1; o < 16; o <<= 1) lt += __shfl_xor(lt, o, 64);
        inv[r] = (lt > 0.f) ? (1.f / lt) : 0.f;
    }
    u16* op = ao + ((size_t)(bbi * 2048 + n0 + w * 16)) * 512 + h * 64;
#pragma unroll
    for (int dt = 0; dt < 4; ++dt)
#pragma unroll
        for (int r = 0; r < 4; ++r)
            op[(size_t)(l4 * 4 + r) * 512 + dt * 16 + l15] = f2bf(acc[dt][r] * inv[r]);
}

// ---------------------------------------------------------------------------
// Inputs: FLOAT32; output d_out: FLOAT32 (32 MB). 4 launches total.
// xn (bf16, 16MB) lives in d_out[0..16MB) (o_gemm overwrites all 32MB).
// ws use ~= 28 MB + 16 KB.
// ---------------------------------------------------------------------------
extern "C" void kernel_launch(void* const* d_in, const int* in_sizes, int n_in,
                              void* d_out, int out_size, void* d_ws, size_t ws_size,
                              hipStream_t stream) {
    const float* x = (const float*)d_in[0];
    const float* media = (const float*)d_in[1];
    const unsigned char* mask = (const unsigned char*)d_in[2];
    const float* ln_g = (const float*)d_in[3];
    const float* ln_b = (const float*)d_in[4];
    const float* Wq = (const float*)d_in[5];
    const float* Wkv = (const float*)d_in[6];
    const float* Wo = (const float*)d_in[7];
    float* out = (float*)d_out;

    char* w = (char*)d_ws;
    unsigned char* mask8 = (unsigned char*)w; w += 4096;
    int* idx = (int*)w;    w += 2048 * 4;
    int* cnts = (int*)w;   w += 256;
    u16* qb = (u16*)w;     w += (size_t)8192 * 512 * 2;
    u16* kvb = (u16*)w;    w += (size_t)2048 * 1024 * 2;
    u16* ao = (u16*)w;     w += (size_t)8192 * 512 * 2;
    u16* mediab = (u16*)w; w += (size_t)2048 * 1024 * 2;
    u16* wqt = (u16*)w;    w += (size_t)512 * 1024 * 2;
    u16* wkvt = (u16*)w;   w += (size_t)1024 * 1024 * 2;
    u16* wot = (u16*)w;    w += (size_t)1024 * 512 * 2;
    u16* xn = (u16*)d_out;

    prep_all<<<3841, 256, 0, stream>>>(x, media, mask, ln_g, ln_b, Wq, Wkv, Wo,
                                       xn, mediab, mask8, idx, cnts, wqt, wkvt, wot);
    qkv_gemm<<<384, 256, 0, stream>>>(xn, wqt, qb, mediab, wkvt, kvb, idx, cnts);
    attn_mfma<<<dim3(32, 8, 4), 256, 0, stream>>>(qb, kvb, cnts, ao);
    o_gemm<<<dim3(8, 64), 256, 0, stream>>>(ao, wot, out);
}